// Round 7
// baseline (397.978 us; speedup 1.0000x reference)
//
#include <hip/hip_runtime.h>

#define NN 100000
#define NE 1200000
#define NG 8
#define DIM 64
#define SCAN_BS 256
#define NB ((NN + SCAN_BS - 1) / SCAN_BS)  // 391
#define TILE 128
#define COLCAP (NE + 3 * NN)  // max padded CSR slots

// histogram partition
#define RANGE 16000   // nodes per range -> 62.5 KB LDS
#define NR 7          // ceil(100000/16000)
#define GSL 16        // edge slices (E % GSL == 0)

// ---- range-partitioned LDS histogram: partial[job][RANGE], job = dir*NR*GSL + r*GSL + g ----
__global__ __launch_bounds__(256) void hist_kernel(const int* __restrict__ esrc,
                                                   const int* __restrict__ edst,
                                                   int* __restrict__ partial, int E) {
  __shared__ int h[RANGE];
  int job = blockIdx.x;
  int g = job % GSL;
  int r = (job / GSL) % NR;
  int dir = job / (GSL * NR);
  const int* __restrict__ idx = dir ? edst : esrc;
  int lo = r * RANGE, hi = min(lo + RANGE, NN);
  for (int i = threadIdx.x; i < RANGE; i += 256) h[i] = 0;
  __syncthreads();
  int s0 = g * (E / GSL), s1 = s0 + E / GSL;
  for (int i = s0 + threadIdx.x; i < s1; i += 256) {
    int v = idx[i];
    if (v >= lo && v < hi) atomicAdd(&h[v - lo], 1);
  }
  __syncthreads();
  int* dst = partial + (size_t)job * RANGE;
  for (int i = threadIdx.x; i < hi - lo; i += 256) dst[i] = h[i];
}

// ---- reduce partials -> indeg (int), snorm/dnorm (float) ----
__global__ void reduce_kernel(const int* __restrict__ partial, int* __restrict__ indeg,
                              float* __restrict__ snormA, float* __restrict__ dnormA, int N) {
  int t = blockIdx.x * blockDim.x + threadIdx.x;
  if (t >= 2 * N) return;
  int dir = t >= N;
  int n = dir ? t - N : t;
  int r = n / RANGE, off = n - r * RANGE;
  const int* p = partial + ((size_t)(dir * NR * GSL + r * GSL)) * RANGE + off;
  int s = 0;
#pragma unroll
  for (int g = 0; g < GSL; ++g) s += p[(size_t)g * RANGE];
  float nv = rsqrtf(fmaxf((float)s, 1.0f));
  if (dir) { indeg[n] = s; dnormA[n] = nv; }
  else snormA[n] = nv;
}

// ---- xs = features * snorm ----
__global__ void prescale_kernel(const float* __restrict__ f, const float* __restrict__ snormA,
                                float* __restrict__ xs, int N) {
  int i = blockIdx.x * blockDim.x + threadIdx.x;
  if (i < N * 16) {
    int n = i >> 4;
    float sn = snormA[n];
    float4 v = ((const float4*)f)[i];
    v.x *= sn; v.y *= sn; v.z *= sn; v.w *= sn;
    ((float4*)xs)[i] = v;
  }
}

// ---- exclusive scan of ceil4(indeg) -> rp2 ----
__global__ __launch_bounds__(SCAN_BS) void scan1_kernel(const int* __restrict__ indeg,
                                                        int* __restrict__ rp2,
                                                        int* __restrict__ bsum, int N) {
  __shared__ int t[SCAN_BS];
  int i = blockIdx.x * SCAN_BS + threadIdx.x;
  int v = (i < N) ? ((indeg[i] + 3) & ~3) : 0;
  t[threadIdx.x] = v;
  __syncthreads();
  for (int off = 1; off < SCAN_BS; off <<= 1) {
    int u = (threadIdx.x >= off) ? t[threadIdx.x - off] : 0;
    __syncthreads();
    t[threadIdx.x] += u;
    __syncthreads();
  }
  if (i < N) rp2[i] = t[threadIdx.x] - v;
  if (i == N - 1) rp2[N] = t[threadIdx.x];
  if (threadIdx.x == SCAN_BS - 1) bsum[blockIdx.x] = t[threadIdx.x];
}

__global__ __launch_bounds__(512) void scan2_kernel(const int* __restrict__ bsum,
                                                    int* __restrict__ boff, int nb) {
  __shared__ int t[512];
  int v = ((int)threadIdx.x < nb) ? bsum[threadIdx.x] : 0;
  t[threadIdx.x] = v;
  __syncthreads();
  for (int off = 1; off < 512; off <<= 1) {
    int u = (threadIdx.x >= off) ? t[threadIdx.x - off] : 0;
    __syncthreads();
    t[threadIdx.x] += u;
    __syncthreads();
  }
  boff[threadIdx.x] = t[threadIdx.x] - v;
}

__global__ __launch_bounds__(SCAN_BS) void scan3_kernel(int* __restrict__ rp2,
                                                        const int* __restrict__ boff, int N) {
  int i = blockIdx.x * SCAN_BS + threadIdx.x;
  if (i < N) rp2[i] += boff[blockIdx.x];
  if (i == N - 1) rp2[N] += boff[blockIdx.x];
}

// ---- init col with NN (zero-row index) ----
__global__ void colinit_kernel(int4* __restrict__ col4, int n4) {
  int i = blockIdx.x * blockDim.x + threadIdx.x;
  int st = gridDim.x * blockDim.x;
  for (; i < n4; i += st) col4[i] = make_int4(NN, NN, NN, NN);
}

// ---- fill CSR col (aligned base) ----
__global__ void fill_kernel(const int* __restrict__ esrc, const int* __restrict__ edst,
                            const int* __restrict__ rp2, int* __restrict__ cnt,
                            int* __restrict__ col, int E) {
  int i = blockIdx.x * blockDim.x + threadIdx.x;
  int st = gridDim.x * blockDim.x;
  for (; i < E; i += st) {
    int d = edst[i];
    int p = atomicAdd(&cnt[d], 1);
    col[rp2[d] + p] = esrc[i];
  }
}

// ---- gather: y[n] = dnorm[n] * sum_{slots} xs[col]; 4 nodes/wave, no LDS/shfl ----
__global__ __launch_bounds__(256, 8) void gather_kernel(
    const float* __restrict__ xs, const float* __restrict__ dnormA,
    const int* __restrict__ rp2, const int* __restrict__ col,
    float* __restrict__ y, int N) {
  const int lane = threadIdx.x & 63;
  const int wid = threadIdx.x >> 6;
  const int g = lane >> 4;
  const int t4 = (lane & 15) << 2;
  const int waveId = blockIdx.x * 4 + wid;
  const int stride4 = gridDim.x * 16;

  for (int n4 = waveId * 4; n4 < N; n4 += stride4) {
    int n = n4 + g;
    bool valid = n < N;
    int nc = valid ? n : 0;
    int base = rp2[nc];
    int end = rp2[nc + 1];
    float4 acc = make_float4(0.f, 0.f, 0.f, 0.f);
    for (int p = base; p < end; p += 4) {
      int4 cs = *(const int4*)(col + p);  // 16B-aligned, group-uniform
      float4 v0 = *(const float4*)(xs + (size_t)cs.x * DIM + t4);
      float4 v1 = *(const float4*)(xs + (size_t)cs.y * DIM + t4);
      float4 v2 = *(const float4*)(xs + (size_t)cs.z * DIM + t4);
      float4 v3 = *(const float4*)(xs + (size_t)cs.w * DIM + t4);
      acc.x += (v0.x + v1.x) + (v2.x + v3.x);
      acc.y += (v0.y + v1.y) + (v2.y + v3.y);
      acc.z += (v0.z + v1.z) + (v2.z + v3.z);
      acc.w += (v0.w + v1.w) + (v2.w + v3.w);
    }
    if (valid) {
      float dn = dnormA[n];
      acc.x *= dn; acc.y *= dn; acc.z *= dn; acc.w *= dn;
      *(float4*)(y + (size_t)n * DIM + t4) = acc;
    }
  }
}

// ---- MLP: out = relu(y @ W + b); POOL=0: in-place write *snorm; POOL=1: fused pooling ----
template <int POOL>
__global__ __launch_bounds__(256) void mlp_kernel(
    float* __restrict__ Y, const float* __restrict__ snormA,
    const float* __restrict__ W, const float* __restrict__ b,
    const int* __restrict__ gid, float* __restrict__ gsum, float* __restrict__ gcnt, int N) {
  __shared__ float Xl[TILE][DIM + 1];
  __shared__ float Wl[DIM][DIM];
  __shared__ float bl[DIM];
  __shared__ float lsum[NG * DIM];
  __shared__ float lcnt[NG];
  const int t = threadIdx.x;
  const int nb = blockIdx.x * TILE;

  for (int i = t; i < DIM * DIM / 4; i += 256)
    ((float4*)&Wl[0][0])[i] = ((const float4*)W)[i];
  if (t < DIM / 4) ((float4*)bl)[t] = ((const float4*)b)[t];
#pragma unroll
  for (int r = 0; r < 8; ++r) {
    int i = t + r * 256;
    int node = i >> 4, c4 = (i & 15) << 2;
    int n = nb + node;
    float4 v = make_float4(0.f, 0.f, 0.f, 0.f);
    if (n < N) v = *(const float4*)(Y + (size_t)n * DIM + c4);
    *(float4*)&Xl[node][c4] = v;
  }
  if (POOL) {
    for (int i = t; i < NG * DIM; i += 256) lsum[i] = 0.0f;
    if (t < NG) lcnt[t] = 0.0f;
  }
  __syncthreads();

  const int node = t & (TILE - 1);
  const int j0 = (t >> 7) << 5;  // 0 or 32
  float acc[32];
#pragma unroll
  for (int u = 0; u < 8; ++u) {
    float4 bb = *(const float4*)&bl[j0 + u * 4];
    acc[u * 4 + 0] = bb.x; acc[u * 4 + 1] = bb.y;
    acc[u * 4 + 2] = bb.z; acc[u * 4 + 3] = bb.w;
  }
  for (int k = 0; k < DIM; k += 4) {
    float4 a4 = *(const float4*)&Xl[node][k];
    float a[4] = {a4.x, a4.y, a4.z, a4.w};
#pragma unroll
    for (int kk = 0; kk < 4; ++kk) {
      float ak = a[kk];
#pragma unroll
      for (int u = 0; u < 8; ++u) {
        float4 w = *(const float4*)&Wl[k + kk][j0 + u * 4];
        acc[u * 4 + 0] = fmaf(ak, w.x, acc[u * 4 + 0]);
        acc[u * 4 + 1] = fmaf(ak, w.y, acc[u * 4 + 1]);
        acc[u * 4 + 2] = fmaf(ak, w.z, acc[u * 4 + 2]);
        acc[u * 4 + 3] = fmaf(ak, w.w, acc[u * 4 + 3]);
      }
    }
  }
#pragma unroll
  for (int u = 0; u < 32; ++u) acc[u] = fmaxf(acc[u], 0.0f);
  __syncthreads();
#pragma unroll
  for (int u = 0; u < 8; ++u)
    *(float4*)&Xl[node][j0 + u * 4] = make_float4(acc[u * 4], acc[u * 4 + 1], acc[u * 4 + 2], acc[u * 4 + 3]);
  __syncthreads();

  if (POOL) {
    for (int i = t; i < TILE * DIM; i += 256) {
      int nd = i >> 6, d = i & 63;
      int n = nb + nd;
      if (n < N) atomicAdd(&lsum[gid[n] * DIM + d], Xl[nd][d]);
    }
    for (int i = t; i < TILE; i += 256)
      if (nb + i < N) atomicAdd(&lcnt[gid[nb + i]], 1.0f);
    __syncthreads();
    for (int i = t; i < NG * DIM; i += 256) atomicAdd(&gsum[i], lsum[i]);
    if (t < NG) atomicAdd(&gcnt[t], lcnt[t]);
  } else {
#pragma unroll
    for (int r = 0; r < 8; ++r) {
      int i = t + r * 256;
      int nd = i >> 4, c4 = (i & 15) << 2;
      int n = nb + nd;
      if (n < N) {
        float sn = snormA[n];
        float4 v = *(const float4*)&Xl[nd][c4];
        v.x *= sn; v.y *= sn; v.z *= sn; v.w *= sn;
        *(float4*)(Y + (size_t)n * DIM + c4) = v;
      }
    }
  }
}

// ---- head ----
__global__ void final_kernel(const float* __restrict__ gsum, const float* __restrict__ gcnt,
                             const float* __restrict__ Wp, const float* __restrict__ bp,
                             float* __restrict__ out) {
  int lane = threadIdx.x;  // 64
#pragma unroll
  for (int g = 0; g < NG; ++g) {
    float inv = 1.0f / fmaxf(gcnt[g], 1.0f);
    float hv = gsum[g * DIM + lane] * inv;
#pragma unroll
    for (int c = 0; c < 2; ++c) {
      float p = hv * Wp[lane * 2 + c];
      for (int off = 32; off; off >>= 1) p += __shfl_down(p, off, 64);
      if (lane == 0) out[g * 2 + c] = p + bp[c];
    }
  }
}

extern "C" void kernel_launch(void* const* d_in, const int* in_sizes, int n_in,
                              void* d_out, int out_size, void* d_ws, size_t ws_size,
                              hipStream_t stream) {
  const float* features = (const float*)d_in[0];
  const float* W1 = (const float*)d_in[1];
  const float* b1 = (const float*)d_in[2];
  const float* W2 = (const float*)d_in[3];
  const float* b2 = (const float*)d_in[4];
  const float* Wp = (const float*)d_in[5];
  const float* bp = (const float*)d_in[6];
  const int* esrc = (const int*)d_in[7];
  const int* edst = (const int*)d_in[8];
  const int* gid = (const int*)d_in[9];
  float* out = (float*)d_out;

  const int N = NN, E = NE;

  float* base = (float*)d_ws;
  size_t off = 0;
  auto alloc = [&](size_t nwords) { size_t r = off; off = (off + nwords + 15) & ~(size_t)15; return r; };

  int* cnt    = (int*)(base + alloc(N));       // zeroed
  float* gsum = base + alloc(NG * DIM);        // zeroed
  float* gcnt = base + alloc(NG);              // zeroed
  size_t zeroWords = off;
  int* indeg  = (int*)(base + alloc(N));
  float* snormA = base + alloc(N);
  float* dnormA = base + alloc(N);
  int* rp2   = (int*)(base + alloc(N + 1));
  int* bsum  = (int*)(base + alloc(512));
  int* boff  = (int*)(base + alloc(512));
  int* col   = (int*)(base + alloc(COLCAP));
  float* xs  = base + alloc((size_t)(N + 1) * DIM);  // partial aliases here until prescale
  float* B   = base + alloc((size_t)(N + 1) * DIM);
  int* partial = (int*)xs;  // 2*NR*GSL*RANGE = 3.584M words < 6.4M

  hipMemsetAsync(d_ws, 0, zeroWords * sizeof(float), stream);
  hipMemsetAsync(xs + (size_t)N * DIM, 0, DIM * sizeof(float), stream);
  hipMemsetAsync(B + (size_t)N * DIM, 0, DIM * sizeof(float), stream);

  hist_kernel<<<2 * NR * GSL, 256, 0, stream>>>(esrc, edst, partial, E);
  reduce_kernel<<<(2 * N + 255) / 256, 256, 0, stream>>>(partial, indeg, snormA, dnormA, N);

  scan1_kernel<<<NB, SCAN_BS, 0, stream>>>(indeg, rp2, bsum, N);
  scan2_kernel<<<1, 512, 0, stream>>>(bsum, boff, NB);
  scan3_kernel<<<NB, SCAN_BS, 0, stream>>>(rp2, boff, N);

  colinit_kernel<<<1465, 256, 0, stream>>>((int4*)col, COLCAP / 4);
  fill_kernel<<<2048, 256, 0, stream>>>(esrc, edst, rp2, cnt, col, E);

  prescale_kernel<<<(N * 16 + 255) / 256, 256, 0, stream>>>(features, snormA, xs, N);

  // layer 1
  gather_kernel<<<2048, 256, 0, stream>>>(xs, dnormA, rp2, col, B, N);
  mlp_kernel<0><<<(N + TILE - 1) / TILE, 256, 0, stream>>>(B, snormA, W1, b1, gid, gsum, gcnt, N);
  // layer 2 (gather into xs buffer; pooling fused into MLP)
  gather_kernel<<<2048, 256, 0, stream>>>(B, dnormA, rp2, col, xs, N);
  mlp_kernel<1><<<(N + TILE - 1) / TILE, 256, 0, stream>>>(xs, snormA, W2, b2, gid, gsum, gcnt, N);

  final_kernel<<<1, 64, 0, stream>>>(gsum, gcnt, Wp, bp, out);
}

// Round 8
// 304.671 us; speedup vs baseline: 1.3063x; 1.3063x over previous
//
#include <hip/hip_runtime.h>

#define NN 100000
#define NE 1200000
#define NG 8
#define DIM 64
#define SCAN_BS 256
#define NB ((NN + SCAN_BS - 1) / SCAN_BS)  // 391
#define TILE 128
#define COLCAP (NE + 3 * NN)

// histogram partition: 13 ranges x 8192 nodes (32KB LDS), 28 edge slices
#define RANGE 8192
#define NR 13
#define GSL 28
#define SLICE4 ((NE / 4 + GSL - 1) / GSL)  // int4 units per slice

// ---- range-partitioned LDS histogram: partial[(dir*NR+r)*GSL+g][RANGE] ----
__global__ __launch_bounds__(256) void hist_kernel(const int4* __restrict__ esrc4,
                                                   const int4* __restrict__ edst4,
                                                   int* __restrict__ partial) {
  __shared__ int h[RANGE];
  int job = blockIdx.x;
  int g = job % GSL;
  int r = (job / GSL) % NR;
  int dir = job / (GSL * NR);
  const int4* __restrict__ idx = dir ? edst4 : esrc4;
  int lo = r * RANGE, hi = min(lo + RANGE, NN);
  for (int i = threadIdx.x; i < RANGE / 4; i += 256) ((int4*)h)[i] = make_int4(0, 0, 0, 0);
  __syncthreads();
  int s0 = g * SLICE4, s1 = min(s0 + SLICE4, NE / 4);
  for (int i = s0 + threadIdx.x; i < s1; i += 256) {
    int4 v = idx[i];
    if (v.x >= lo && v.x < hi) atomicAdd(&h[v.x - lo], 1);
    if (v.y >= lo && v.y < hi) atomicAdd(&h[v.y - lo], 1);
    if (v.z >= lo && v.z < hi) atomicAdd(&h[v.z - lo], 1);
    if (v.w >= lo && v.w < hi) atomicAdd(&h[v.w - lo], 1);
  }
  __syncthreads();
  int4* dst = (int4*)(partial + (size_t)job * RANGE);
  int cap4 = (hi - lo) >> 2;  // 8192 or 1696, both %4==0
  for (int i = threadIdx.x; i < cap4; i += 256) dst[i] = ((int4*)h)[i];
}

// ---- reduce partials -> indeg, snorm/dnorm ----
__global__ void reduce_kernel(const int* __restrict__ partial, int* __restrict__ indeg,
                              float* __restrict__ snormA, float* __restrict__ dnormA, int N) {
  int t = blockIdx.x * blockDim.x + threadIdx.x;
  if (t >= 2 * N) return;
  int dir = t >= N;
  int n = dir ? t - N : t;
  int r = n >> 13, off = n & (RANGE - 1);
  const int* p = partial + (((size_t)dir * NR + r) * GSL) * RANGE + off;
  int s = 0;
#pragma unroll
  for (int g = 0; g < GSL; ++g) s += p[(size_t)g * RANGE];
  float nv = rsqrtf(fmaxf((float)s, 1.0f));
  if (dir) { indeg[n] = s; dnormA[n] = nv; }
  else snormA[n] = nv;
}

// ---- exclusive scan of ceil4(indeg) -> rp2 ----
__global__ __launch_bounds__(SCAN_BS) void scan1_kernel(const int* __restrict__ indeg,
                                                        int* __restrict__ rp2,
                                                        int* __restrict__ bsum, int N) {
  __shared__ int t[SCAN_BS];
  int i = blockIdx.x * SCAN_BS + threadIdx.x;
  int v = (i < N) ? ((indeg[i] + 3) & ~3) : 0;
  t[threadIdx.x] = v;
  __syncthreads();
  for (int off = 1; off < SCAN_BS; off <<= 1) {
    int u = (threadIdx.x >= off) ? t[threadIdx.x - off] : 0;
    __syncthreads();
    t[threadIdx.x] += u;
    __syncthreads();
  }
  if (i < N) rp2[i] = t[threadIdx.x] - v;
  if (i == N - 1) rp2[N] = t[threadIdx.x];
  if (threadIdx.x == SCAN_BS - 1) bsum[blockIdx.x] = t[threadIdx.x];
}

__global__ __launch_bounds__(512) void scan2_kernel(const int* __restrict__ bsum,
                                                    int* __restrict__ boff, int nb) {
  __shared__ int t[512];
  int v = ((int)threadIdx.x < nb) ? bsum[threadIdx.x] : 0;
  t[threadIdx.x] = v;
  __syncthreads();
  for (int off = 1; off < 512; off <<= 1) {
    int u = (threadIdx.x >= off) ? t[threadIdx.x - off] : 0;
    __syncthreads();
    t[threadIdx.x] += u;
    __syncthreads();
  }
  boff[threadIdx.x] = t[threadIdx.x] - v;
}

__global__ __launch_bounds__(SCAN_BS) void scan3_kernel(int* __restrict__ rp2,
                                                        const int* __restrict__ boff, int N) {
  int i = blockIdx.x * SCAN_BS + threadIdx.x;
  if (i < N) rp2[i] += boff[blockIdx.x];
  if (i == N - 1) rp2[N] += boff[blockIdx.x];
}

// ---- in-place: partial[1][r][g][i] -> absolute start offset (rp2 + excl-scan over g) ----
__global__ void offscan_kernel(int* __restrict__ partial, const int* __restrict__ rp2, int N) {
  int n = blockIdx.x * blockDim.x + threadIdx.x;  // over NR*RANGE, == node id
  if (n >= N) return;
  int r = n >> 13, i = n & (RANGE - 1);
  int* p = partial + (((size_t)NR + r) * GSL) * RANGE + i;
  int running = rp2[n];
#pragma unroll
  for (int g = 0; g < GSL; ++g) {
    int tmp = p[(size_t)g * RANGE];
    p[(size_t)g * RANGE] = running;
    running += tmp;
  }
}

// ---- init col with NN (zero-row index) ----
__global__ void colinit_kernel(int4* __restrict__ col4, int n4) {
  int i = blockIdx.x * blockDim.x + threadIdx.x;
  int st = gridDim.x * blockDim.x;
  for (; i < n4; i += st) col4[i] = make_int4(NN, NN, NN, NN);
}

// ---- fill CSR col: LDS-offset slot assignment, no global atomics ----
__global__ __launch_bounds__(256) void fill_kernel(const int4* __restrict__ esrc4,
                                                   const int4* __restrict__ edst4,
                                                   const int* __restrict__ partial,
                                                   int* __restrict__ col) {
  __shared__ int cnt[RANGE];
  int job = blockIdx.x;  // NR*GSL
  int g = job % GSL, r = job / GSL;
  int lo = r * RANGE, hi = min(lo + RANGE, NN);
  const int* off = partial + (((size_t)NR + r) * GSL + g) * RANGE;
  for (int i = threadIdx.x; i < hi - lo; i += 256) cnt[i] = off[i];
  __syncthreads();
  int s0 = g * SLICE4, s1 = min(s0 + SLICE4, NE / 4);
  for (int i = s0 + threadIdx.x; i < s1; i += 256) {
    int4 d = edst4[i];
    int4 s = esrc4[i];
    if (d.x >= lo && d.x < hi) col[atomicAdd(&cnt[d.x - lo], 1)] = s.x;
    if (d.y >= lo && d.y < hi) col[atomicAdd(&cnt[d.y - lo], 1)] = s.y;
    if (d.z >= lo && d.z < hi) col[atomicAdd(&cnt[d.z - lo], 1)] = s.z;
    if (d.w >= lo && d.w < hi) col[atomicAdd(&cnt[d.w - lo], 1)] = s.w;
  }
}

// ---- xs = features * snorm ----
__global__ void prescale_kernel(const float* __restrict__ f, const float* __restrict__ snormA,
                                float* __restrict__ xs, int N) {
  int i = blockIdx.x * blockDim.x + threadIdx.x;
  if (i < N * 16) {
    int n = i >> 4;
    float sn = snormA[n];
    float4 v = ((const float4*)f)[i];
    v.x *= sn; v.y *= sn; v.z *= sn; v.w *= sn;
    ((float4*)xs)[i] = v;
  }
}

// ---- gather: y[n] = dnorm[n] * sum_{slots} xs[col]; 4 nodes/wave ----
__global__ __launch_bounds__(256, 8) void gather_kernel(
    const float* __restrict__ xs, const float* __restrict__ dnormA,
    const int* __restrict__ rp2, const int* __restrict__ col,
    float* __restrict__ y, int N) {
  const int lane = threadIdx.x & 63;
  const int wid = threadIdx.x >> 6;
  const int g = lane >> 4;
  const int t4 = (lane & 15) << 2;
  const int waveId = blockIdx.x * 4 + wid;
  const int stride4 = gridDim.x * 16;

  for (int n4 = waveId * 4; n4 < N; n4 += stride4) {
    int n = n4 + g;
    bool valid = n < N;
    int nc = valid ? n : 0;
    int base = rp2[nc];
    int end = rp2[nc + 1];
    float4 acc = make_float4(0.f, 0.f, 0.f, 0.f);
    for (int p = base; p < end; p += 4) {
      int4 cs = *(const int4*)(col + p);
      float4 v0 = *(const float4*)(xs + (size_t)cs.x * DIM + t4);
      float4 v1 = *(const float4*)(xs + (size_t)cs.y * DIM + t4);
      float4 v2 = *(const float4*)(xs + (size_t)cs.z * DIM + t4);
      float4 v3 = *(const float4*)(xs + (size_t)cs.w * DIM + t4);
      acc.x += (v0.x + v1.x) + (v2.x + v3.x);
      acc.y += (v0.y + v1.y) + (v2.y + v3.y);
      acc.z += (v0.z + v1.z) + (v2.z + v3.z);
      acc.w += (v0.w + v1.w) + (v2.w + v3.w);
    }
    if (valid) {
      float dn = dnormA[n];
      acc.x *= dn; acc.y *= dn; acc.z *= dn; acc.w *= dn;
      *(float4*)(y + (size_t)n * DIM + t4) = acc;
    }
  }
}

// ---- MLP: out = relu(y @ W + b); POOL=0: in-place write *snorm; POOL=1: fused pooling ----
template <int POOL>
__global__ __launch_bounds__(256) void mlp_kernel(
    float* __restrict__ Y, const float* __restrict__ snormA,
    const float* __restrict__ W, const float* __restrict__ b,
    const int* __restrict__ gid, float* __restrict__ gsum, float* __restrict__ gcnt, int N) {
  __shared__ float Xl[TILE][DIM + 1];
  __shared__ float Wl[DIM][DIM];
  __shared__ float bl[DIM];
  __shared__ float lsum[NG * DIM];
  __shared__ float lcnt[NG];
  const int t = threadIdx.x;
  const int nb = blockIdx.x * TILE;

  for (int i = t; i < DIM * DIM / 4; i += 256)
    ((float4*)&Wl[0][0])[i] = ((const float4*)W)[i];
  if (t < DIM / 4) ((float4*)bl)[t] = ((const float4*)b)[t];
#pragma unroll
  for (int r = 0; r < 8; ++r) {
    int i = t + r * 256;
    int node = i >> 4, c4 = (i & 15) << 2;
    int n = nb + node;
    float4 v = make_float4(0.f, 0.f, 0.f, 0.f);
    if (n < N) v = *(const float4*)(Y + (size_t)n * DIM + c4);
    *(float4*)&Xl[node][c4] = v;
  }
  if (POOL) {
    for (int i = t; i < NG * DIM; i += 256) lsum[i] = 0.0f;
    if (t < NG) lcnt[t] = 0.0f;
  }
  __syncthreads();

  const int node = t & (TILE - 1);
  const int j0 = (t >> 7) << 5;  // 0 or 32
  float acc[32];
#pragma unroll
  for (int u = 0; u < 8; ++u) {
    float4 bb = *(const float4*)&bl[j0 + u * 4];
    acc[u * 4 + 0] = bb.x; acc[u * 4 + 1] = bb.y;
    acc[u * 4 + 2] = bb.z; acc[u * 4 + 3] = bb.w;
  }
  for (int k = 0; k < DIM; k += 4) {
    float4 a4 = *(const float4*)&Xl[node][k];
    float a[4] = {a4.x, a4.y, a4.z, a4.w};
#pragma unroll
    for (int kk = 0; kk < 4; ++kk) {
      float ak = a[kk];
#pragma unroll
      for (int u = 0; u < 8; ++u) {
        float4 w = *(const float4*)&Wl[k + kk][j0 + u * 4];
        acc[u * 4 + 0] = fmaf(ak, w.x, acc[u * 4 + 0]);
        acc[u * 4 + 1] = fmaf(ak, w.y, acc[u * 4 + 1]);
        acc[u * 4 + 2] = fmaf(ak, w.z, acc[u * 4 + 2]);
        acc[u * 4 + 3] = fmaf(ak, w.w, acc[u * 4 + 3]);
      }
    }
  }
#pragma unroll
  for (int u = 0; u < 32; ++u) acc[u] = fmaxf(acc[u], 0.0f);
  __syncthreads();
#pragma unroll
  for (int u = 0; u < 8; ++u)
    *(float4*)&Xl[node][j0 + u * 4] = make_float4(acc[u * 4], acc[u * 4 + 1], acc[u * 4 + 2], acc[u * 4 + 3]);
  __syncthreads();

  if (POOL) {
    for (int i = t; i < TILE * DIM; i += 256) {
      int nd = i >> 6, d = i & 63;
      int n = nb + nd;
      if (n < N) atomicAdd(&lsum[gid[n] * DIM + d], Xl[nd][d]);
    }
    for (int i = t; i < TILE; i += 256)
      if (nb + i < N) atomicAdd(&lcnt[gid[nb + i]], 1.0f);
    __syncthreads();
    for (int i = t; i < NG * DIM; i += 256) atomicAdd(&gsum[i], lsum[i]);
    if (t < NG) atomicAdd(&gcnt[t], lcnt[t]);
  } else {
#pragma unroll
    for (int r = 0; r < 8; ++r) {
      int i = t + r * 256;
      int nd = i >> 4, c4 = (i & 15) << 2;
      int n = nb + nd;
      if (n < N) {
        float sn = snormA[n];
        float4 v = *(const float4*)&Xl[nd][c4];
        v.x *= sn; v.y *= sn; v.z *= sn; v.w *= sn;
        *(float4*)(Y + (size_t)n * DIM + c4) = v;
      }
    }
  }
}

// ---- head ----
__global__ void final_kernel(const float* __restrict__ gsum, const float* __restrict__ gcnt,
                             const float* __restrict__ Wp, const float* __restrict__ bp,
                             float* __restrict__ out) {
  int lane = threadIdx.x;  // 64
#pragma unroll
  for (int g = 0; g < NG; ++g) {
    float inv = 1.0f / fmaxf(gcnt[g], 1.0f);
    float hv = gsum[g * DIM + lane] * inv;
#pragma unroll
    for (int c = 0; c < 2; ++c) {
      float p = hv * Wp[lane * 2 + c];
      for (int off = 32; off; off >>= 1) p += __shfl_down(p, off, 64);
      if (lane == 0) out[g * 2 + c] = p + bp[c];
    }
  }
}

extern "C" void kernel_launch(void* const* d_in, const int* in_sizes, int n_in,
                              void* d_out, int out_size, void* d_ws, size_t ws_size,
                              hipStream_t stream) {
  const float* features = (const float*)d_in[0];
  const float* W1 = (const float*)d_in[1];
  const float* b1 = (const float*)d_in[2];
  const float* W2 = (const float*)d_in[3];
  const float* b2 = (const float*)d_in[4];
  const float* Wp = (const float*)d_in[5];
  const float* bp = (const float*)d_in[6];
  const int* esrc = (const int*)d_in[7];
  const int* edst = (const int*)d_in[8];
  const int* gid = (const int*)d_in[9];
  float* out = (float*)d_out;

  const int N = NN;

  float* base = (float*)d_ws;
  size_t off = 0;
  auto alloc = [&](size_t nwords) { size_t r = off; off = (off + nwords + 15) & ~(size_t)15; return r; };

  float* gsum = base + alloc(NG * DIM);   // zeroed
  float* gcnt = base + alloc(NG);         // zeroed
  size_t zeroWords = off;
  int* indeg  = (int*)(base + alloc(N));
  float* snormA = base + alloc(N);
  float* dnormA = base + alloc(N);
  int* rp2   = (int*)(base + alloc(N + 1));
  int* bsum  = (int*)(base + alloc(512));
  int* boff  = (int*)(base + alloc(512));
  int* col   = (int*)(base + alloc(COLCAP));
  float* xs  = base + alloc((size_t)(N + 1) * DIM);  // partial aliases here (5.97M < 6.4M words)
  float* B   = base + alloc((size_t)(N + 1) * DIM);
  int* partial = (int*)xs;  // 2*NR*GSL*RANGE = 5,963,776 ints

  hipMemsetAsync(d_ws, 0, zeroWords * sizeof(float), stream);
  hipMemsetAsync(xs + (size_t)N * DIM, 0, DIM * sizeof(float), stream);
  hipMemsetAsync(B + (size_t)N * DIM, 0, DIM * sizeof(float), stream);

  hist_kernel<<<2 * NR * GSL, 256, 0, stream>>>((const int4*)esrc, (const int4*)edst, partial);
  reduce_kernel<<<(2 * N + 255) / 256, 256, 0, stream>>>(partial, indeg, snormA, dnormA, N);

  scan1_kernel<<<NB, SCAN_BS, 0, stream>>>(indeg, rp2, bsum, N);
  scan2_kernel<<<1, 512, 0, stream>>>(bsum, boff, NB);
  scan3_kernel<<<NB, SCAN_BS, 0, stream>>>(rp2, boff, N);

  offscan_kernel<<<(NR * RANGE + 255) / 256, 256, 0, stream>>>(partial, rp2, N);
  colinit_kernel<<<1465, 256, 0, stream>>>((int4*)col, COLCAP / 4);
  fill_kernel<<<NR * GSL, 256, 0, stream>>>((const int4*)esrc, (const int4*)edst, partial, col);

  prescale_kernel<<<(N * 16 + 255) / 256, 256, 0, stream>>>(features, snormA, xs, N);

  // layer 1
  gather_kernel<<<2048, 256, 0, stream>>>(xs, dnormA, rp2, col, B, N);
  mlp_kernel<0><<<(N + TILE - 1) / TILE, 256, 0, stream>>>(B, snormA, W1, b1, gid, gsum, gcnt, N);
  // layer 2
  gather_kernel<<<2048, 256, 0, stream>>>(B, dnormA, rp2, col, xs, N);
  mlp_kernel<1><<<(N + TILE - 1) / TILE, 256, 0, stream>>>(xs, snormA, W2, b2, gid, gsum, gcnt, N);

  final_kernel<<<1, 64, 0, stream>>>(gsum, gcnt, Wp, bp, out);
}

// Round 9
// 278.993 us; speedup vs baseline: 1.4265x; 1.0920x over previous
//
#include <hip/hip_runtime.h>

#define NN 100000
#define NE 1200000
#define NG 8
#define DIM 64
#define SCAN_BS 256
#define NB ((NN + SCAN_BS - 1) / SCAN_BS)  // 391
#define COLCAP (NE + 3 * NN)

// histogram partition: 13 ranges x 8192 nodes (32KB LDS), 28 edge slices
#define RANGE 8192
#define NR 13
#define GSL 28
#define SLICE4 ((NE / 4 + GSL - 1) / GSL)  // int4 units per slice

__device__ __forceinline__ float readlane_f(float v, int l) {
  return __uint_as_float(__builtin_amdgcn_readlane(__float_as_uint(v), l));
}

// ---- range-partitioned LDS histogram: partial[(dir*NR+r)*GSL+g][RANGE] ----
__global__ __launch_bounds__(256) void hist_kernel(const int4* __restrict__ esrc4,
                                                   const int4* __restrict__ edst4,
                                                   int* __restrict__ partial) {
  __shared__ int h[RANGE];
  int job = blockIdx.x;
  int g = job % GSL;
  int r = (job / GSL) % NR;
  int dir = job / (GSL * NR);
  const int4* __restrict__ idx = dir ? edst4 : esrc4;
  int lo = r * RANGE, hi = min(lo + RANGE, NN);
  for (int i = threadIdx.x; i < RANGE / 4; i += 256) ((int4*)h)[i] = make_int4(0, 0, 0, 0);
  __syncthreads();
  int s0 = g * SLICE4, s1 = min(s0 + SLICE4, NE / 4);
  for (int i = s0 + threadIdx.x; i < s1; i += 256) {
    int4 v = idx[i];
    if (v.x >= lo && v.x < hi) atomicAdd(&h[v.x - lo], 1);
    if (v.y >= lo && v.y < hi) atomicAdd(&h[v.y - lo], 1);
    if (v.z >= lo && v.z < hi) atomicAdd(&h[v.z - lo], 1);
    if (v.w >= lo && v.w < hi) atomicAdd(&h[v.w - lo], 1);
  }
  __syncthreads();
  int4* dst = (int4*)(partial + (size_t)job * RANGE);
  int cap4 = (hi - lo) >> 2;
  for (int i = threadIdx.x; i < cap4; i += 256) dst[i] = ((int4*)h)[i];
}

// ---- reduce partials -> indeg, snorm/dnorm ----
__global__ void reduce_kernel(const int* __restrict__ partial, int* __restrict__ indeg,
                              float* __restrict__ snormA, float* __restrict__ dnormA, int N) {
  int t = blockIdx.x * blockDim.x + threadIdx.x;
  if (t >= 2 * N) return;
  int dir = t >= N;
  int n = dir ? t - N : t;
  int r = n >> 13, off = n & (RANGE - 1);
  const int* p = partial + (((size_t)dir * NR + r) * GSL) * RANGE + off;
  int s = 0;
#pragma unroll
  for (int g = 0; g < GSL; ++g) s += p[(size_t)g * RANGE];
  float nv = rsqrtf(fmaxf((float)s, 1.0f));
  if (dir) { indeg[n] = s; dnormA[n] = nv; }
  else snormA[n] = nv;
}

// ---- exclusive scan of ceil4(indeg) -> rp2 ----
__global__ __launch_bounds__(SCAN_BS) void scan1_kernel(const int* __restrict__ indeg,
                                                        int* __restrict__ rp2,
                                                        int* __restrict__ bsum, int N) {
  __shared__ int t[SCAN_BS];
  int i = blockIdx.x * SCAN_BS + threadIdx.x;
  int v = (i < N) ? ((indeg[i] + 3) & ~3) : 0;
  t[threadIdx.x] = v;
  __syncthreads();
  for (int off = 1; off < SCAN_BS; off <<= 1) {
    int u = (threadIdx.x >= off) ? t[threadIdx.x - off] : 0;
    __syncthreads();
    t[threadIdx.x] += u;
    __syncthreads();
  }
  if (i < N) rp2[i] = t[threadIdx.x] - v;
  if (i == N - 1) rp2[N] = t[threadIdx.x];
  if (threadIdx.x == SCAN_BS - 1) bsum[blockIdx.x] = t[threadIdx.x];
}

__global__ __launch_bounds__(512) void scan2_kernel(const int* __restrict__ bsum,
                                                    int* __restrict__ boff, int nb) {
  __shared__ int t[512];
  int v = ((int)threadIdx.x < nb) ? bsum[threadIdx.x] : 0;
  t[threadIdx.x] = v;
  __syncthreads();
  for (int off = 1; off < 512; off <<= 1) {
    int u = (threadIdx.x >= off) ? t[threadIdx.x - off] : 0;
    __syncthreads();
    t[threadIdx.x] += u;
    __syncthreads();
  }
  boff[threadIdx.x] = t[threadIdx.x] - v;
}

__global__ __launch_bounds__(SCAN_BS) void scan3_kernel(int* __restrict__ rp2,
                                                        const int* __restrict__ boff, int N) {
  int i = blockIdx.x * SCAN_BS + threadIdx.x;
  if (i < N) rp2[i] += boff[blockIdx.x];
  if (i == N - 1) rp2[N] += boff[blockIdx.x];
}

// ---- in-place: partial[1][r][g][i] -> absolute start offset ----
__global__ void offscan_kernel(int* __restrict__ partial, const int* __restrict__ rp2, int N) {
  int n = blockIdx.x * blockDim.x + threadIdx.x;
  if (n >= N) return;
  int r = n >> 13, i = n & (RANGE - 1);
  int* p = partial + (((size_t)NR + r) * GSL) * RANGE + i;
  int running = rp2[n];
#pragma unroll
  for (int g = 0; g < GSL; ++g) {
    int tmp = p[(size_t)g * RANGE];
    p[(size_t)g * RANGE] = running;
    running += tmp;
  }
}

// ---- init col with NN (zero-row index) ----
__global__ void colinit_kernel(int4* __restrict__ col4, int n4) {
  int i = blockIdx.x * blockDim.x + threadIdx.x;
  int st = gridDim.x * blockDim.x;
  for (; i < n4; i += st) col4[i] = make_int4(NN, NN, NN, NN);
}

// ---- fill CSR col: LDS-offset slot assignment, no global atomics ----
__global__ __launch_bounds__(256) void fill_kernel(const int4* __restrict__ esrc4,
                                                   const int4* __restrict__ edst4,
                                                   const int* __restrict__ partial,
                                                   int* __restrict__ col) {
  __shared__ int cnt[RANGE];
  int job = blockIdx.x;  // NR*GSL
  int g = job % GSL, r = job / GSL;
  int lo = r * RANGE, hi = min(lo + RANGE, NN);
  const int* off = partial + (((size_t)NR + r) * GSL + g) * RANGE;
  for (int i = threadIdx.x; i < hi - lo; i += 256) cnt[i] = off[i];
  __syncthreads();
  int s0 = g * SLICE4, s1 = min(s0 + SLICE4, NE / 4);
  for (int i = s0 + threadIdx.x; i < s1; i += 256) {
    int4 d = edst4[i];
    int4 s = esrc4[i];
    if (d.x >= lo && d.x < hi) col[atomicAdd(&cnt[d.x - lo], 1)] = s.x;
    if (d.y >= lo && d.y < hi) col[atomicAdd(&cnt[d.y - lo], 1)] = s.y;
    if (d.z >= lo && d.z < hi) col[atomicAdd(&cnt[d.z - lo], 1)] = s.z;
    if (d.w >= lo && d.w < hi) col[atomicAdd(&cnt[d.w - lo], 1)] = s.w;
  }
}

// ---- xs = features * snorm ----
__global__ void prescale_kernel(const float* __restrict__ f, const float* __restrict__ snormA,
                                float* __restrict__ xs, int N) {
  int i = blockIdx.x * blockDim.x + threadIdx.x;
  if (i < N * 16) {
    int n = i >> 4;
    float sn = snormA[n];
    float4 v = ((const float4*)f)[i];
    v.x *= sn; v.y *= sn; v.z *= sn; v.w *= sn;
    ((float4*)xs)[i] = v;
  }
}

// ---- gather: y[n] = dnorm[n] * sum_{slots} xs[col]; 4 nodes/wave ----
__global__ __launch_bounds__(256, 8) void gather_kernel(
    const float* __restrict__ xs, const float* __restrict__ dnormA,
    const int* __restrict__ rp2, const int* __restrict__ col,
    float* __restrict__ y, int N) {
  const int lane = threadIdx.x & 63;
  const int wid = threadIdx.x >> 6;
  const int g = lane >> 4;
  const int t4 = (lane & 15) << 2;
  const int waveId = blockIdx.x * 4 + wid;
  const int stride4 = gridDim.x * 16;

  for (int n4 = waveId * 4; n4 < N; n4 += stride4) {
    int n = n4 + g;
    bool valid = n < N;
    int nc = valid ? n : 0;
    int base = rp2[nc];
    int end = rp2[nc + 1];
    float4 acc = make_float4(0.f, 0.f, 0.f, 0.f);
    for (int p = base; p < end; p += 4) {
      int4 cs = *(const int4*)(col + p);
      float4 v0 = *(const float4*)(xs + (size_t)cs.x * DIM + t4);
      float4 v1 = *(const float4*)(xs + (size_t)cs.y * DIM + t4);
      float4 v2 = *(const float4*)(xs + (size_t)cs.z * DIM + t4);
      float4 v3 = *(const float4*)(xs + (size_t)cs.w * DIM + t4);
      acc.x += (v0.x + v1.x) + (v2.x + v3.x);
      acc.y += (v0.y + v1.y) + (v2.y + v3.y);
      acc.z += (v0.z + v1.z) + (v2.z + v3.z);
      acc.w += (v0.w + v1.w) + (v2.w + v3.w);
    }
    if (valid) {
      float dn = dnormA[n];
      acc.x *= dn; acc.y *= dn; acc.z *= dn; acc.w *= dn;
      *(float4*)(y + (size_t)n * DIM + t4) = acc;
    }
  }
}

// ---- MLP: r = relu(y@W+b); W register-resident, wave streams nodes ----
// POOL=0: in-place write *snorm; POOL=1: fused graph pooling
template <int POOL>
__global__ __launch_bounds__(256, 4) void mlp_kernel(
    float* __restrict__ Y, const float* __restrict__ snormA,
    const float* __restrict__ W, const float* __restrict__ b,
    const int* __restrict__ gid, float* __restrict__ gsum, float* __restrict__ gcnt, int N) {
  __shared__ float lsum[NG * DIM];
  __shared__ float lcnt[NG];
  if (POOL) {
    for (int i = threadIdx.x; i < NG * DIM; i += 256) lsum[i] = 0.0f;
    if (threadIdx.x < NG) lcnt[threadIdx.x] = 0.0f;
    __syncthreads();
  }
  const int lane = threadIdx.x & 63;
  const int wid = threadIdx.x >> 6;

  // whole W register-resident: wreg[k] = W[k][lane]  (64 VGPRs, static idx only)
  float wreg[DIM];
#pragma unroll
  for (int k = 0; k < DIM; ++k) wreg[k] = W[k * DIM + lane];
  const float bv = b[lane];

  const int waveId = blockIdx.x * 4 + wid;
  const int nw = gridDim.x * 4;
  for (int n = waveId; n < N; n += nw) {
    float a = Y[(size_t)n * DIM + lane];
    float r0 = bv, r1 = 0.f, r2 = 0.f, r3 = 0.f;
#pragma unroll
    for (int k = 0; k < DIM; k += 4) {
      r0 = fmaf(readlane_f(a, k + 0), wreg[k + 0], r0);
      r1 = fmaf(readlane_f(a, k + 1), wreg[k + 1], r1);
      r2 = fmaf(readlane_f(a, k + 2), wreg[k + 2], r2);
      r3 = fmaf(readlane_f(a, k + 3), wreg[k + 3], r3);
    }
    float r = fmaxf((r0 + r1) + (r2 + r3), 0.0f);
    if (POOL) {
      int g = gid[n];
      atomicAdd(&lsum[g * DIM + lane], r);
      if (lane == 0) atomicAdd(&lcnt[g], 1.0f);
    } else {
      Y[(size_t)n * DIM + lane] = r * snormA[n];
    }
  }
  if (POOL) {
    __syncthreads();
    for (int i = threadIdx.x; i < NG * DIM; i += 256) atomicAdd(&gsum[i], lsum[i]);
    if (threadIdx.x < NG) atomicAdd(&gcnt[threadIdx.x], lcnt[threadIdx.x]);
  }
}

// ---- head ----
__global__ void final_kernel(const float* __restrict__ gsum, const float* __restrict__ gcnt,
                             const float* __restrict__ Wp, const float* __restrict__ bp,
                             float* __restrict__ out) {
  int lane = threadIdx.x;  // 64
#pragma unroll
  for (int g = 0; g < NG; ++g) {
    float inv = 1.0f / fmaxf(gcnt[g], 1.0f);
    float hv = gsum[g * DIM + lane] * inv;
#pragma unroll
    for (int c = 0; c < 2; ++c) {
      float p = hv * Wp[lane * 2 + c];
      for (int off = 32; off; off >>= 1) p += __shfl_down(p, off, 64);
      if (lane == 0) out[g * 2 + c] = p + bp[c];
    }
  }
}

extern "C" void kernel_launch(void* const* d_in, const int* in_sizes, int n_in,
                              void* d_out, int out_size, void* d_ws, size_t ws_size,
                              hipStream_t stream) {
  const float* features = (const float*)d_in[0];
  const float* W1 = (const float*)d_in[1];
  const float* b1 = (const float*)d_in[2];
  const float* W2 = (const float*)d_in[3];
  const float* b2 = (const float*)d_in[4];
  const float* Wp = (const float*)d_in[5];
  const float* bp = (const float*)d_in[6];
  const int* esrc = (const int*)d_in[7];
  const int* edst = (const int*)d_in[8];
  const int* gid = (const int*)d_in[9];
  float* out = (float*)d_out;

  const int N = NN;

  float* base = (float*)d_ws;
  size_t off = 0;
  auto alloc = [&](size_t nwords) { size_t r = off; off = (off + nwords + 15) & ~(size_t)15; return r; };

  float* gsum = base + alloc(NG * DIM);   // zeroed
  float* gcnt = base + alloc(NG);         // zeroed
  size_t zeroWords = off;
  int* indeg  = (int*)(base + alloc(N));
  float* snormA = base + alloc(N);
  float* dnormA = base + alloc(N);
  int* rp2   = (int*)(base + alloc(N + 1));
  int* bsum  = (int*)(base + alloc(512));
  int* boff  = (int*)(base + alloc(512));
  int* col   = (int*)(base + alloc(COLCAP));
  float* xs  = base + alloc((size_t)(N + 1) * DIM);  // partial aliases here
  float* B   = base + alloc((size_t)(N + 1) * DIM);
  int* partial = (int*)xs;  // 2*NR*GSL*RANGE = 5,963,776 ints < 6.4M words

  hipMemsetAsync(d_ws, 0, zeroWords * sizeof(float), stream);
  hipMemsetAsync(xs + (size_t)N * DIM, 0, DIM * sizeof(float), stream);
  hipMemsetAsync(B + (size_t)N * DIM, 0, DIM * sizeof(float), stream);

  hist_kernel<<<2 * NR * GSL, 256, 0, stream>>>((const int4*)esrc, (const int4*)edst, partial);
  reduce_kernel<<<(2 * N + 255) / 256, 256, 0, stream>>>(partial, indeg, snormA, dnormA, N);

  scan1_kernel<<<NB, SCAN_BS, 0, stream>>>(indeg, rp2, bsum, N);
  scan2_kernel<<<1, 512, 0, stream>>>(bsum, boff, NB);
  scan3_kernel<<<NB, SCAN_BS, 0, stream>>>(rp2, boff, N);

  offscan_kernel<<<(NR * RANGE + 255) / 256, 256, 0, stream>>>(partial, rp2, N);
  colinit_kernel<<<1465, 256, 0, stream>>>((int4*)col, COLCAP / 4);
  fill_kernel<<<NR * GSL, 256, 0, stream>>>((const int4*)esrc, (const int4*)edst, partial, col);

  prescale_kernel<<<(N * 16 + 255) / 256, 256, 0, stream>>>(features, snormA, xs, N);

  // layer 1
  gather_kernel<<<2048, 256, 0, stream>>>(xs, dnormA, rp2, col, B, N);
  mlp_kernel<0><<<1024, 256, 0, stream>>>(B, snormA, W1, b1, gid, gsum, gcnt, N);
  // layer 2
  gather_kernel<<<2048, 256, 0, stream>>>(B, dnormA, rp2, col, xs, N);
  mlp_kernel<1><<<1024, 256, 0, stream>>>(xs, snormA, W2, b2, gid, gsum, gcnt, N);

  final_kernel<<<1, 64, 0, stream>>>(gsum, gcnt, Wp, bp, out);
}